// Round 1
// baseline (639.039 us; speedup 1.0000x reference)
//
#include <hip/hip_runtime.h>

// Stacked LSTM B=2048,T=512,IN=4,H=64,L=4,OUT=5 — barrier-synchronized SKEWED
// pipeline (replaces R10/R11 async flag-ring).
// Grid 256 (1 block/CU), block 1024 = 16 waves; waves 4l..4l+3 = layer l, NB=8.
// Iteration i: layer l computes t = i - l (skew). Every dependency edge
// (own h(t-1), prev-layer h(t)) crosses exactly one iteration -> ONE
// __syncthreads per iteration, 2-slot parity buffer (read slot i&1, write
// slot (i+1)&1). No flags/polls/atomics/s_sleep: the ring burned ~1700
// cyc/step of VALU issue + release-drain on the protocol (VALUBusy 63% vs
// ~1100 cyc useful); the HW barrier sleeps waves instead.
// Lockstep-skew unlocks:
//  * input frags for layer l>0 read DIRECTLY from layer l-1's own-h region
//    (same phi layout, same slot parity) -> wI duplicate write deleted,
//    RSTR 136->72 (row = 144 B, 16B-aligned).
//  * x preloaded once into LDS as f16 (32 KB); layer-0 builds its x A-frag
//    in registers (q==0 lanes, ln&2==0) -> zero global loads in the loop,
//    so the barrier's vmcnt(0) drain never waits on HBM.
//  * layer-0 skips kt=3 MFMA (Wf[.][3] identically 0 for l==0: exact).
// Math identical to R10 (validated absmax 4.9e-4): single-plane f16
// weights+acts, prescale -log2e (i,f,o) / +2log2e (g) -> direct exp2;
// zero-C MFMA, bias in pointwise; phi(u)=4*(u&15)+(u>>4) K-permutation;
// row-spread rho(b)=4*(b>>1)+(b&1); 16 (12 for l=0) MFMA/wave/step.

#define B_    2048
#define T_    512
#define H_    64
#define OUT_  5
#define RSTR  72               // f16/row = 144 B (16B-aligned)
#define LOG2E 1.44269504088896340736f

typedef _Float16 f16;
typedef __attribute__((ext_vector_type(4))) _Float16 f16x4;
typedef __attribute__((ext_vector_type(8))) _Float16 f16x8;
typedef __attribute__((ext_vector_type(4))) float f32x4;

__device__ __forceinline__ float rcpf(float v) { return __builtin_amdgcn_rcpf(v); }
__device__ __forceinline__ float ex2(float v)  { return __builtin_amdgcn_exp2f(v); }

__global__ __launch_bounds__(1024, 4) void lstm_skew_k(
    const float* __restrict__ x,      // [B,T,4]
    const float* __restrict__ W_ih0,  // [256,4]
    const float* __restrict__ W_ihr,  // [3,256,64]
    const float* __restrict__ W_hh,   // [4,256,64]
    const float* __restrict__ b_ih,   // [4,256]
    const float* __restrict__ b_hh,   // [4,256]
    const float* __restrict__ W_fc,   // [5,64]
    const float* __restrict__ b_fc,   // [5]
    float* __restrict__ out)          // [B,5]
{
    const int tid  = threadIdx.x;
    const int wave = tid >> 6;        // 0..15
    const int l    = wave >> 2;       // layer 0..3
    const int jj   = wave & 3;        // quarter of the layer's units
    const int lane = tid & 63;
    const int q    = lane >> 4;
    const int ln   = lane & 15;
    const int u    = jj * 16 + ln;    // owned hidden unit
    const int b0   = blockIdx.x * 8;

    // [layer][slot 0..1][row][col 0..63 own h (phi layout)]. 36.9 KB.
    __shared__ f16  buf[4][2][16][RSTR];
    __shared__ f16  xlds[T_ * 32];     // [t][b(8)][e(4)] f16, 32 KB
    __shared__ float hf[8][H_ + 1];    // FC staging

    for (int k = tid; k < (int)(sizeof(buf) / 4); k += 1024) ((unsigned*)buf)[k] = 0u;

    // ---- one-time x preload -> xlds (f16), coalesced float4 reads ----
#pragma unroll
    for (int k = 0; k < 4; ++k) {
        const int idx = tid + k * 1024;              // 0..4095
        const int bb  = idx >> 9, tt = idx & 511;
        const float4 v = *(const float4*)(x + (size_t)(b0 + bb) * (T_ * 4) + tt * 4);
        f16x4 h4; h4[0] = (f16)v.x; h4[1] = (f16)v.y; h4[2] = (f16)v.z; h4[3] = (f16)v.w;
        *(f16x4*)&xlds[tt * 32 + bb * 4] = h4;
    }

    // ---- weights -> f16 B-frags (4 gates x 4 K-tiles = 64 VGPRs), prescaled ----
    const float* Whh = W_hh + (size_t)l * 256 * 64;
    const float* Wih = (l == 0) ? W_ih0 : (W_ihr + (size_t)(l - 1) * 256 * 64);
    const float scg[4] = {-LOG2E, -LOG2E, 2.0f * LOG2E, -LOG2E};

    f16x8 Wf[4][4];                   // [gate][kt]; Wf[.][3] all-zero for l==0
    float biasv[4];
#pragma unroll
    for (int g4 = 0; g4 < 4; ++g4) {
        const int n = g4 * 64 + u;
        biasv[g4] = (b_ih[l * 256 + n] + b_hh[l * 256 + n]) * scg[g4];
#pragma unroll
        for (int kt = 0; kt < 4; ++kt) {
            f16x8 f;
#pragma unroll
            for (int e = 0; e < 8; ++e) {
                const int kap = kt * 32 + q * 8 + e;
                float wv;
                if (kap < 64) {
                    const int k = ((kap & 3) << 4) | (kap >> 2);   // phi^-1
                    wv = Whh[n * 64 + k];
                } else {
                    const int kk = kap - 64;
                    if (l == 0) wv = (kk < 4) ? Wih[n * 4 + kk] : 0.0f;
                    else { const int k = ((kk & 3) << 4) | (kk >> 2); wv = Wih[n * 64 + k]; }
                }
                f[e] = (f16)(wv * scg[g4]);
            }
            Wf[g4][kt] = f;
        }
    }

    // ---- per-lane pointers (both parities precomputed) ----
    const int rdOff = ln * RSTR;
    const f16* hRd0 = &buf[l][0][0][0] + rdOff;
    const f16* hRd1 = &buf[l][1][0][0] + rdOff;
    const int  lp   = (l > 0) ? (l - 1) : 0;
    const f16* iRd0 = &buf[lp][0][0][0] + rdOff;   // prev layer own-h = my input
    const f16* iRd1 = &buf[lp][1][0][0] + rdOff;
    const int owOff = 4 * q * RSTR + 4 * ln + jj;  // own h (rows 4q+rr, col phi(u))
    f16* hWr0 = &buf[l][0][0][0] + owOff;
    f16* hWr1 = &buf[l][1][0][0] + owOff;

    // layer-0 x-fragment: A2 row=ln valid iff (ln&2)==0; batch = 2*(ln>>2)+(ln&1)
    const int  xb  = 2 * (ln >> 2) + (ln & 1);
    const bool xok = (l == 0) && (q == 0) && ((ln & 2) == 0);
    const f16* xP  = &xlds[xb * 4];

    __syncthreads();                 // zero-init + xlds visible

    const f32x4 Z0 = {0.f, 0.f, 0.f, 0.f};
    float cst[2] = {0.f, 0.f};       // c-state (batches 2q+rr)

    auto step = [&](const int i, const f16* hb, const f16* ib, f16* wOb) {
        const int t = i - l;                       // this layer's timestep
        if ((unsigned)t < T_) {                    // wave-uniform activity guard
            f16x8 A0 = *(const f16x8*)(hb + q * 8);
            f16x8 A1 = *(const f16x8*)(hb + 32 + q * 8);
            f16x8 A2;
            if (l == 0) {
#pragma unroll
                for (int e = 0; e < 8; ++e) A2[e] = (f16)0;
                if (xok) {
                    const f16x4 xv = *(const f16x4*)(xP + t * 32);
                    A2[0] = xv[0]; A2[1] = xv[1]; A2[2] = xv[2]; A2[3] = xv[3];
                }
            } else {
                A2 = *(const f16x8*)(ib + q * 8);
            }

            f32x4 acc[4];
#pragma unroll
            for (int g4 = 0; g4 < 4; ++g4)
                acc[g4] = __builtin_amdgcn_mfma_f32_16x16x32_f16(A0, Wf[g4][0], Z0, 0, 0, 0);
#pragma unroll
            for (int g4 = 0; g4 < 4; ++g4)
                acc[g4] = __builtin_amdgcn_mfma_f32_16x16x32_f16(A1, Wf[g4][1], acc[g4], 0, 0, 0);
#pragma unroll
            for (int g4 = 0; g4 < 4; ++g4)
                acc[g4] = __builtin_amdgcn_mfma_f32_16x16x32_f16(A2, Wf[g4][2], acc[g4], 0, 0, 0);
            if (l != 0) {                          // kt=3 B-frag is exactly 0 for l==0
                const f16x8 A3 = *(const f16x8*)(ib + 32 + q * 8);
#pragma unroll
                for (int g4 = 0; g4 < 4; ++g4)
                    acc[g4] = __builtin_amdgcn_mfma_f32_16x16x32_f16(A3, Wf[g4][3], acc[g4], 0, 0, 0);
            }

            // ---- pointwise: 2 updates (batches 2q+rr, unit u) ----
#pragma unroll
            for (int rr = 0; rr < 2; ++rr) {
                const float si = rcpf(1.0f + ex2(acc[0][rr] + biasv[0]));
                const float sf = rcpf(1.0f + ex2(acc[1][rr] + biasv[1]));
                const float tg = 1.0f - 2.0f * rcpf(1.0f + ex2(acc[2][rr] + biasv[2]));
                const float so = rcpf(1.0f + ex2(acc[3][rr] + biasv[3]));
                const float c  = sf * cst[rr] + si * tg;
                cst[rr] = c;
                const float tc = 1.0f - 2.0f * rcpf(1.0f + ex2(c * (2.0f * LOG2E)));
                const float h  = so * tc;
                wOb[rr * RSTR] = (f16)h;           // own h(t) -> opposite slot
                if (l == 3 && t == T_ - 1) hf[2 * q + rr][u] = h;
            }
        }
        __syncthreads();                           // the ONE barrier per iteration
    };

#pragma unroll 1
    for (int i = 0; i < 516; i += 2) {             // 512 steps + 3 skew (+1 pad)
        step(i,     hRd0, iRd0, hWr1);             // read slot 0, write slot 1
        step(i + 1, hRd1, iRd1, hWr0);             // read slot 1, write slot 0
    }

    // ---- FC on h(T-1) of layer 3 (hf visible via final barrier) ----
    if (tid < 8 * OUT_) {
        const int b = tid / OUT_, o = tid % OUT_;
        float a = b_fc[o];
#pragma unroll
        for (int k = 0; k < H_; ++k)
            a = fmaf(hf[b][k], W_fc[o * H_ + k], a);
        out[(b0 + b) * OUT_ + o] = a;
    }
}

extern "C" void kernel_launch(void* const* d_in, const int* in_sizes, int n_in,
                              void* d_out, int out_size, void* d_ws, size_t ws_size,
                              hipStream_t stream) {
    const float* x     = (const float*)d_in[0];
    const float* W_ih0 = (const float*)d_in[1];
    const float* W_ihr = (const float*)d_in[2];
    const float* W_hh  = (const float*)d_in[3];
    const float* b_ih  = (const float*)d_in[4];
    const float* b_hh  = (const float*)d_in[5];
    const float* W_fc  = (const float*)d_in[6];
    const float* b_fc  = (const float*)d_in[7];
    float* out = (float*)d_out;

    lstm_skew_k<<<dim3(B_ / 8), dim3(1024), 0, stream>>>(
        x, W_ih0, W_ihr, W_hh, b_ih, b_hh, W_fc, b_fc, out);
}